// Round 1
// baseline (258.325 us; speedup 1.0000x reference)
//
#include <hip/hip_runtime.h>

// SparseMaxPool: out[b,d,r,c] = max(x[b,d,r..c]) on a sparse (r,c) pattern, else 0.
// Valid offsets o=c-r: 0..15 (any r), odd 17..31 (r%2==0), o%4==3 in 35..63 (r%4==0),
// o%8==7 in 71..127 (r%8==0).  Window max via LDS sparse table (doubling).

#define NN 128
#define SLICE_ELEMS (NN * NN)

__device__ __forceinline__ float entry_val(const float* __restrict__ buf, int r, int c) {
    int o = c - r;
    int w = o + 1;
    int wcl = w < 1 ? 1 : w;          // clamp so clz is safe for c<r lanes
    int k = 31 - __clz(wcl);          // floor(log2(w))
    int p2 = 1 << k;
    int lb = 129 * k - (p2 - 1);      // level-k base in buf (0,128,255,380,501,614,711,776)
    int d2 = wcl - p2;                // second read offset: w - 2^k
    int oc = o < 1 ? 1 : o;
    int t = 31 - __clz(oc);           // floor(log2(o)) for o>=1
    int sh = t - 3;                   // stride shift: o in [2^t,2^{t+1}) -> t-3, clamped [0,3]
    sh = sh < 0 ? 0 : (sh > 3 ? 3 : sh);
    int m = (1 << sh) - 1;
    bool valid = (o >= 0) & ((o & m) == m) & ((r & m) == 0);
    // In-bounds even for invalid lanes: lb+r+d2 <= 903 < 1040 (buf padded)
    float v = fmaxf(buf[lb + r], buf[lb + r + d2]);
    return valid ? v : 0.0f;
}

__global__ __launch_bounds__(256) void sparse_maxpool_kernel(
        const float* __restrict__ x, float* __restrict__ out) {
    __shared__ float buf[1040];       // sparse table: levels 0..7 concatenated (777 used, padded)
    const int tid = threadIdx.x;
    const int slice = blockIdx.x;     // b*256 + d, 4096 total

    // Level 0 = x slice
    if (tid < NN) buf[tid] = x[(size_t)slice * NN + tid];
    __syncthreads();

    // Levels 1..7: P[k][i] = max(P[k-1][i], P[k-1][i + 2^{k-1}]), len = 129 - 2^k
    int base_prev = 0, base_cur = NN;
    #pragma unroll
    for (int k = 1; k <= 7; ++k) {
        int half = 1 << (k - 1);
        int len = (NN + 1) - (1 << k);
        if (tid < len)
            buf[base_cur + tid] = fmaxf(buf[base_prev + tid], buf[base_prev + tid + half]);
        __syncthreads();
        base_prev = base_cur;
        base_cur += len;
    }

    // Write phase: 16384 floats per slice as 4096 float4, 16 per thread, coalesced.
    float4* __restrict__ out_s = reinterpret_cast<float4*>(out + (size_t)slice * SLICE_ELEMS);
    #pragma unroll
    for (int it = 0; it < 16; ++it) {
        int idx = it * 256 + tid;     // float4 index in slice
        int r = idx >> 5;             // 32 float4 per row
        int c0 = (idx & 31) << 2;
        float4 v;
        v.x = entry_val(buf, r, c0);
        v.y = entry_val(buf, r, c0 + 1);
        v.z = entry_val(buf, r, c0 + 2);
        v.w = entry_val(buf, r, c0 + 3);
        out_s[idx] = v;
    }
}

extern "C" void kernel_launch(void* const* d_in, const int* in_sizes, int n_in,
                              void* d_out, int out_size, void* d_ws, size_t ws_size,
                              hipStream_t stream) {
    const float* x = (const float*)d_in[0];
    float* out = (float*)d_out;
    const int slices = in_sizes[0] / NN;   // 16*256 = 4096
    sparse_maxpool_kernel<<<dim3(slices), dim3(256), 0, stream>>>(x, out);
}